// Round 4
// baseline (472.409 us; speedup 1.0000x reference)
//
#include <hip/hip_runtime.h>
#include <hip/hip_bf16.h>

typedef unsigned short ushortT;
typedef unsigned int uintT;
typedef __attribute__((ext_vector_type(8))) short bf16x8;
typedef __attribute__((ext_vector_type(4))) float f32x4;
typedef __attribute__((ext_vector_type(4))) unsigned short us4;

__device__ __forceinline__ ushortT f2bf(float f) {
    union { float f; uintT u; } x; x.f = f;
    uintT r = x.u + 0x7fffu + ((x.u >> 16) & 1u);
    return (ushortT)(r >> 16);
}
__device__ __forceinline__ float bf2f(ushortT u) {
    union { uintT u; float f; } x; x.u = ((uintT)u) << 16; return x.f;
}

#define ZLD 520   // Zt row stride in elements (512 + 8 pad)

// ---------------------------------------------------------------------------
// K0: column-softmax of W1/W2, e = emb @ sW, row-normalize.  grid=2 (e1, e2)
// ---------------------------------------------------------------------------
__global__ __launch_bounds__(256) void k_embed(const float* __restrict__ emb,
                                               const float* __restrict__ W1,
                                               const float* __restrict__ W2,
                                               float* __restrict__ e1,
                                               float* __restrict__ e2) {
    __shared__ float sW[800];
    __shared__ float sWs[800];
    const float* W = (blockIdx.x == 0) ? W1 : W2;
    float* e = (blockIdx.x == 0) ? e1 : e2;
    int tid = threadIdx.x;
    for (int i = tid; i < 800; i += 256) sW[i] = W[i];
    __syncthreads();
    if (tid < 20) {
        float mx = -1e30f;
        for (int i = 0; i < 40; ++i) mx = fmaxf(mx, sW[i * 20 + tid]);
        float s = 0.f;
        for (int i = 0; i < 40; ++i) s += __expf(sW[i * 20 + tid] - mx);
        float inv = 1.f / s;
        for (int i = 0; i < 40; ++i) sWs[i * 20 + tid] = __expf(sW[i * 20 + tid] - mx) * inv;
    }
    __syncthreads();
    for (int row = tid; row < 512; row += 256) {
        float acc[20];
        #pragma unroll
        for (int j = 0; j < 20; ++j) acc[j] = 0.f;
        for (int i = 0; i < 40; ++i) {
            float ev = emb[row * 40 + i];
            #pragma unroll
            for (int j = 0; j < 20; ++j) acc[j] += ev * sWs[i * 20 + j];
        }
        float s = 0.f;
        #pragma unroll
        for (int j = 0; j < 20; ++j) s += acc[j] * acc[j];
        float scale = 1.f / (sqrtf(s) + 1e-8f);
        #pragma unroll
        for (int j = 0; j < 20; ++j) e[row * 20 + j] = acc[j] * scale;
    }
}

// ---------------------------------------------------------------------------
// K1: A[v][w] = adj>0 ? e1[v].e2[w] + adj : 9e-15 ; d[v] = 1/sqrt(rowsum)
// ---------------------------------------------------------------------------
__global__ __launch_bounds__(256) void k_adj(const float* __restrict__ adj,
                                             const float* __restrict__ e1,
                                             const float* __restrict__ e2,
                                             float* __restrict__ A,
                                             float* __restrict__ d) {
    int v = blockIdx.x, tid = threadIdx.x;
    __shared__ float ev[20];
    if (tid < 20) ev[tid] = e1[v * 20 + tid];
    __syncthreads();
    float local = 0.f;
    for (int w = tid; w < 512; w += 256) {
        float dot = 0.f;
        #pragma unroll
        for (int j = 0; j < 20; ++j) dot += ev[j] * e2[w * 20 + j];
        float av = adj[v * 512 + w];
        float Av = (av > 0.f) ? (dot + av) : 9e-15f;
        A[v * 512 + w] = Av;
        local += Av;
    }
    __shared__ float red[256];
    red[tid] = local;
    __syncthreads();
    for (int s = 128; s > 0; s >>= 1) {
        if (tid < s) red[tid] += red[tid + s];
        __syncthreads();
    }
    if (tid == 0) d[v] = 1.f / sqrtf(red[0]);
}

// ---------------------------------------------------------------------------
// K2: P slot1 = M[w][v] = Ls^T = -d[v]*d[w]*A[v][w] (bf16)
// ---------------------------------------------------------------------------
__global__ __launch_bounds__(256) void k_m(const float* __restrict__ A,
                                           const float* __restrict__ d,
                                           ushortT* __restrict__ P) {
    int w = blockIdx.x, tid = threadIdx.x;
    float dw = d[w];
    for (int v = tid; v < 512; v += 256) {
        float val = -d[v] * dw * A[v * 512 + w];
        P[512 * 512 + w * 512 + v] = f2bf(val);
    }
}

// ---------------------------------------------------------------------------
// K3: merged prep. Blocks 0..159: Wq build. Blocks 160+: x -> xbf convert.
// ---------------------------------------------------------------------------
__global__ __launch_bounds__(256) void k_prep(const float* __restrict__ x,
                                              ushortT* __restrict__ xbf,
                                              const float* __restrict__ mlp_w,
                                              ushortT* __restrict__ Wq) {
    int bx = blockIdx.x;
    if (bx < 160) {
        int idx = bx * 256 + threadIdx.x;
        if (idx >= 10 * 64 * 64) return;
        int q = idx >> 12, rem = idx & 4095, o = rem >> 6, c = rem & 63;
        float v;
        if (q == 0) {
            v = 0.f;
            #pragma unroll
            for (int k = 0; k < 4; ++k) v += mlp_w[o * 832 + k * 64 + c];
        } else {
            v = mlp_w[o * 832 + (q + 3) * 64 + c];
        }
        Wq[idx] = f2bf(v);
    } else {
        size_t i = (size_t)(bx - 160) * 256 + threadIdx.x;
        int c = (int)(i & 15) * 4;
        int v = (int)((i >> 4) & 511);
        int bt = (int)(i >> 13);            // b*12 + t
        int b = bt / 12, t = bt - b * 12;
        f32x4 f = *(const f32x4*)(x + (((size_t)b * 512 + v) * 12 + t) * 64 + c);
        us4 o = { f2bf(f[0]), f2bf(f[1]), f2bf(f[2]), f2bf(f[3]) };
        *(us4*)(xbf + ((size_t)bt * 512 + v) * 64 + c) = o;
    }
}

// ---------------------------------------------------------------------------
// 512x512x512 bf16 MFMA GEMM (+Chebyshev epilogue). Supports a second
// independent GEMM in blocks 64..127 (A2/B2/out3, mode 0).
// ---------------------------------------------------------------------------
__global__ __launch_bounds__(256) void k_gemm512(const ushortT* __restrict__ A,
                                                 const ushortT* __restrict__ B,
                                                 ushortT* __restrict__ out1,
                                                 ushortT* __restrict__ out2,
                                                 int mode,
                                                 const ushortT* __restrict__ aux,
                                                 const ushortT* __restrict__ A2,
                                                 const ushortT* __restrict__ B2,
                                                 ushortT* __restrict__ out3) {
    int bx = blockIdx.x;
    if (bx >= 64) { A = A2; B = B2; out1 = out3; out2 = nullptr; mode = 0; bx -= 64; }
    int wave = threadIdx.x >> 6, lane = threadIdx.x & 63;
    int lr = lane & 15, lg = lane >> 4;
    int mbase = (bx >> 3) * 64;
    int nbase = (bx & 7) * 64 + wave * 16;
    f32x4 acc[4] = {};
    for (int kk = 0; kk < 16; ++kk) {
        int k0 = kk * 32 + lg * 8;
        bf16x8 bfr;
        #pragma unroll
        for (int j = 0; j < 8; ++j) bfr[j] = (short)B[(k0 + j) * 512 + nbase + lr];
        #pragma unroll
        for (int wt = 0; wt < 4; ++wt) {
            bf16x8 af = *(const bf16x8*)(A + (mbase + wt * 16 + lr) * 512 + k0);
            acc[wt] = __builtin_amdgcn_mfma_f32_16x16x32_bf16(af, bfr, acc[wt], 0, 0, 0);
        }
    }
    #pragma unroll
    for (int wt = 0; wt < 4; ++wt)
        #pragma unroll
        for (int r = 0; r < 4; ++r) {
            int row = mbase + wt * 16 + lg * 4 + r;
            int col = nbase + lr;
            float v = acc[wt][r];
            out1[row * 512 + col] = f2bf(v);
            if (mode == 1) out2[row * 512 + col] = f2bf(2.f * v - (row == col ? 1.f : 0.f));
            else if (mode == 2) out2[row * 512 + col] = f2bf(4.f * v - 3.f * bf2f(aux[row * 512 + col]));
        }
}

// ---------------------------------------------------------------------------
// Main fused kernel v4:  out = relu(x + bias + sum_q P_q @ (X @ Wq^T))
//   Depth-4 P prefetch ring (32 VGPR), zphase split into 2 vt-halves to cap
//   register peak < 128, Zt padded stride (520) instead of XOR swizzle.
// ---------------------------------------------------------------------------
template<bool XBF>
__global__ __launch_bounds__(512, 4) void k_main(const float* __restrict__ x,
                                                 const ushortT* __restrict__ xbf,
                                                 const ushortT* __restrict__ P,
                                                 const ushortT* __restrict__ Wq,
                                                 const float* __restrict__ bias,
                                                 float* __restrict__ out) {
    __shared__ ushortT Zt[64 * ZLD];   // Z^T[o][v], padded stride
    const int SZ = 512 * 512;
    int bid = blockIdx.x;
    int b = bid / 24, rr = bid % 24, tt = rr >> 1, half = rr & 1;
    int tid = threadIdx.x, wave = tid >> 6, lane = tid & 63;
    int lr = lane & 15, lg = lane >> 4;
    int wbase = half * 256 + wave * 32;   // wave's 32 output rows
    int vbase = wave * 64;                // wave's 64 Z-compute rows

    const ushortT* xq = xbf + ((size_t)(b * 12 + tt) * 512 + vbase) * 64;
    const float*   xqf = x + ((size_t)(b * 512 + vbase) * 12 + tt) * 64;

    f32x4 oacc[2][4] = {};
    bf16x8 a0r[4], a1r[4];
    // preload ring (q=1, kk=0..3) — no barrier dependency, issue immediately
    {
        const ushortT* pq1 = P + (size_t)SZ + (size_t)(wbase + lr) * 512 + lg * 8;
        #pragma unroll
        for (int s = 0; s < 4; ++s) {
            a0r[s] = *(const bf16x8*)(pq1 + s * 32);
            a1r[s] = *(const bf16x8*)(pq1 + 8192 + s * 32);
        }
    }

    for (int q = 0; q <= 9; ++q) {
        // ---- zphase: Zt = (X @ Wq^T)^T, two vt-halves to cap reg peak ----
        const ushortT* wqp = Wq + q * 4096;
        #pragma unroll
        for (int h = 0; h < 2; ++h) {
            bf16x8 xf[4];
            #pragma unroll
            for (int j = 0; j < 2; ++j) {
                int vrow = (h * 2 + j) * 16 + lr;
                if (XBF) {
                    xf[j * 2 + 0] = *(const bf16x8*)(xq + vrow * 64 + lg * 8);
                    xf[j * 2 + 1] = *(const bf16x8*)(xq + vrow * 64 + 32 + lg * 8);
                } else {
                    const float* px = xqf + (size_t)vrow * 768 + lg * 8;
                    f32x4 f0 = *(const f32x4*)px;
                    f32x4 f1 = *(const f32x4*)(px + 4);
                    f32x4 f2 = *(const f32x4*)(px + 32);
                    f32x4 f3 = *(const f32x4*)(px + 36);
                    bf16x8 v0, v1;
                    v0[0] = (short)f2bf(f0[0]); v0[1] = (short)f2bf(f0[1]);
                    v0[2] = (short)f2bf(f0[2]); v0[3] = (short)f2bf(f0[3]);
                    v0[4] = (short)f2bf(f1[0]); v0[5] = (short)f2bf(f1[1]);
                    v0[6] = (short)f2bf(f1[2]); v0[7] = (short)f2bf(f1[3]);
                    v1[0] = (short)f2bf(f2[0]); v1[1] = (short)f2bf(f2[1]);
                    v1[2] = (short)f2bf(f2[2]); v1[3] = (short)f2bf(f2[3]);
                    v1[4] = (short)f2bf(f3[0]); v1[5] = (short)f2bf(f3[1]);
                    v1[6] = (short)f2bf(f3[2]); v1[7] = (short)f2bf(f3[3]);
                    xf[j * 2 + 0] = v0;
                    xf[j * 2 + 1] = v1;
                }
            }
            #pragma unroll
            for (int ot = 0; ot < 4; ++ot) {
                int o = ot * 16 + lr;
                bf16x8 wf0 = *(const bf16x8*)(wqp + o * 64 + lg * 8);
                bf16x8 wf1 = *(const bf16x8*)(wqp + o * 64 + 32 + lg * 8);
                f32x4 z0 = {}, z1 = {};
                z0 = __builtin_amdgcn_mfma_f32_16x16x32_bf16(xf[0], wf0, z0, 0, 0, 0);
                z0 = __builtin_amdgcn_mfma_f32_16x16x32_bf16(xf[1], wf1, z0, 0, 0, 0);
                z1 = __builtin_amdgcn_mfma_f32_16x16x32_bf16(xf[2], wf0, z1, 0, 0, 0);
                z1 = __builtin_amdgcn_mfma_f32_16x16x32_bf16(xf[3], wf1, z1, 0, 0, 0);
                int zb = o * ZLD;
                {
                    int v0i = vbase + (h * 2 + 0) * 16 + lg * 4;
                    us4 pk = { f2bf(z0[0]), f2bf(z0[1]), f2bf(z0[2]), f2bf(z0[3]) };
                    *(us4*)&Zt[zb + v0i] = pk;
                }
                {
                    int v0i = vbase + (h * 2 + 1) * 16 + lg * 4;
                    us4 pk = { f2bf(z1[0]), f2bf(z1[1]), f2bf(z1[2]), f2bf(z1[3]) };
                    *(us4*)&Zt[zb + v0i] = pk;
                }
            }
        }
        __syncthreads();

        if (q == 0) {
            // identity support: oacc = Z_0 directly
            #pragma unroll
            for (int wt = 0; wt < 2; ++wt)
                #pragma unroll
                for (int ot = 0; ot < 4; ++ot) {
                    int o = ot * 16 + lr;
                    int w0 = wbase + wt * 16 + lg * 4;
                    us4 z4 = *(const us4*)&Zt[o * ZLD + w0];
                    oacc[wt][ot][0] = bf2f(z4[0]);
                    oacc[wt][ot][1] = bf2f(z4[1]);
                    oacc[wt][ot][2] = bf2f(z4[2]);
                    oacc[wt][ot][3] = bf2f(z4[3]);
                }
        } else {
            const ushortT* pq  = P + (size_t)q * SZ + (size_t)(wbase + lr) * 512 + lg * 8;
            const ushortT* pqn = pq + SZ;
            #pragma unroll
            for (int kk = 0; kk < 16; ++kk) {
                const int slot = kk & 3;
                int vb = kk * 32 + lg * 8;
                bf16x8 b0 = *(const bf16x8*)&Zt[(0 * 16 + lr) * ZLD + vb];
                bf16x8 b1 = *(const bf16x8*)&Zt[(1 * 16 + lr) * ZLD + vb];
                bf16x8 b2 = *(const bf16x8*)&Zt[(2 * 16 + lr) * ZLD + vb];
                bf16x8 b3 = *(const bf16x8*)&Zt[(3 * 16 + lr) * ZLD + vb];
                oacc[0][0] = __builtin_amdgcn_mfma_f32_16x16x32_bf16(a0r[slot], b0, oacc[0][0], 0, 0, 0);
                oacc[1][0] = __builtin_amdgcn_mfma_f32_16x16x32_bf16(a1r[slot], b0, oacc[1][0], 0, 0, 0);
                oacc[0][1] = __builtin_amdgcn_mfma_f32_16x16x32_bf16(a0r[slot], b1, oacc[0][1], 0, 0, 0);
                oacc[1][1] = __builtin_amdgcn_mfma_f32_16x16x32_bf16(a1r[slot], b1, oacc[1][1], 0, 0, 0);
                oacc[0][2] = __builtin_amdgcn_mfma_f32_16x16x32_bf16(a0r[slot], b2, oacc[0][2], 0, 0, 0);
                oacc[1][2] = __builtin_amdgcn_mfma_f32_16x16x32_bf16(a1r[slot], b2, oacc[1][2], 0, 0, 0);
                oacc[0][3] = __builtin_amdgcn_mfma_f32_16x16x32_bf16(a0r[slot], b3, oacc[0][3], 0, 0, 0);
                oacc[1][3] = __builtin_amdgcn_mfma_f32_16x16x32_bf16(a1r[slot], b3, oacc[1][3], 0, 0, 0);
                if (kk < 12) {
                    a0r[slot] = *(const bf16x8*)(pq + (kk + 4) * 32);
                    a1r[slot] = *(const bf16x8*)(pq + 8192 + (kk + 4) * 32);
                } else if (q < 9) {
                    a0r[slot] = *(const bf16x8*)(pqn + (kk - 12) * 32);
                    a1r[slot] = *(const bf16x8*)(pqn + 8192 + (kk - 12) * 32);
                }
            }
        }
        __syncthreads();
    }

    // ---- epilogue: residual + bias + relu, fp32 out ----
    #pragma unroll
    for (int wt = 0; wt < 2; ++wt)
        #pragma unroll
        for (int ot = 0; ot < 4; ++ot)
            #pragma unroll
            for (int r = 0; r < 4; ++r) {
                int w = wbase + wt * 16 + lg * 4 + r;
                int o = ot * 16 + lr;
                size_t oi = (((size_t)b * 512 + w) * 12 + tt) * 64 + o;
                float v = oacc[wt][ot][r] + x[oi] + bias[o];
                out[oi] = (v > 0.f) ? v : 0.f;
            }
}

// ---------------------------------------------------------------------------
extern "C" void kernel_launch(void* const* d_in, const int* in_sizes, int n_in,
                              void* d_out, int out_size, void* d_ws, size_t ws_size,
                              hipStream_t stream) {
    const float* x    = (const float*)d_in[0];
    const float* adj  = (const float*)d_in[1];
    const float* emb  = (const float*)d_in[2];
    const float* W1   = (const float*)d_in[3];
    const float* W2   = (const float*)d_in[4];
    const float* mlpw = (const float*)d_in[5];
    const float* mlpb = (const float*)d_in[6];
    float* out = (float*)d_out;

    char* ws = (char*)d_ws;
    float*   e1   = (float*)(ws + 0);
    float*   e2   = (float*)(ws + 65536);
    float*   A    = (float*)(ws + 131072);
    float*   dvec = (float*)(ws + 1179648);
    ushortT* P    = (ushortT*)(ws + 1183744);            // [10][512][512] bf16 (slot0 unused)
    ushortT* Wq   = (ushortT*)(ws + 6426624);            // [10][64][64]  bf16
    ushortT* xbf  = (ushortT*)(ws + 6508544);            // [b][t][512][64] bf16 = 24MB
    const size_t WS_NEED = 6508544 + (size_t)32 * 12 * 512 * 64 * 2;
    const bool use_xbf = (ws_size >= WS_NEED);

    k_embed<<<2, 256, 0, stream>>>(emb, W1, W2, e1, e2);
    k_adj<<<512, 256, 0, stream>>>(adj, e1, e2, A, dvec);
    k_m<<<512, 256, 0, stream>>>(A, dvec, P);
    k_prep<<<use_xbf ? 12448 : 160, 256, 0, stream>>>(x, xbf, mlpw, Wq);

    const int SZ = 512 * 512;
    ushortT *S1 = P + 1 * SZ, *S2 = P + 2 * SZ, *S3 = P + 3 * SZ, *S4 = P + 4 * SZ,
            *S5 = P + 5 * SZ, *S6 = P + 6 * SZ, *S7 = P + 7 * SZ, *S8 = P + 8 * SZ,
            *S9 = P + 9 * SZ;
    // S2 = M^2 ; S4 = 2M^2 - I (T2^T)
    k_gemm512<<<64, 256, 0, stream>>>(S1, S1, S2, S4, 1, nullptr, nullptr, nullptr, nullptr);
    // S3 = M^3 ; S7 = 4M^3 - 3M (T3^T)  ||  S5 = (T2^T)^2
    k_gemm512<<<128, 256, 0, stream>>>(S1, S2, S3, S7, 2, S1, S4, S4, S5);
    // S6 = (T2^T)^3  ||  S8 = (T3^T)^2
    k_gemm512<<<128, 256, 0, stream>>>(S4, S5, S6, nullptr, 0, nullptr, S7, S7, S8);
    // S9 = (T3^T)^3
    k_gemm512<<<64, 256, 0, stream>>>(S7, S8, S9, nullptr, 0, nullptr, nullptr, nullptr, nullptr);

    if (use_xbf)
        k_main<true><<<768, 512, 0, stream>>>(x, xbf, P, Wq, mlpb, out);
    else
        k_main<false><<<768, 512, 0, stream>>>(x, nullptr, P, Wq, mlpb, out);
    (void)in_sizes; (void)n_in; (void)out_size;
}

// Round 5
// 391.845 us; speedup vs baseline: 1.2056x; 1.2056x over previous
//
#include <hip/hip_runtime.h>
#include <hip/hip_bf16.h>

typedef unsigned short ushortT;
typedef unsigned int uintT;
typedef __attribute__((ext_vector_type(8))) short bf16x8;
typedef __attribute__((ext_vector_type(4))) float f32x4;
typedef __attribute__((ext_vector_type(4))) unsigned short us4;

__device__ __forceinline__ ushortT f2bf(float f) {
    union { float f; uintT u; } x; x.f = f;
    uintT r = x.u + 0x7fffu + ((x.u >> 16) & 1u);
    return (ushortT)(r >> 16);
}
__device__ __forceinline__ float bf2f(ushortT u) {
    union { uintT u; float f; } x; x.u = ((uintT)u) << 16; return x.f;
}

#define ZLD 520   // Zt row stride in elements (512 + 8 pad)

// ---------------------------------------------------------------------------
// K0: column-softmax of W1/W2, e = emb @ sW, row-normalize.  grid=2 (e1, e2)
// ---------------------------------------------------------------------------
__global__ __launch_bounds__(256) void k_embed(const float* __restrict__ emb,
                                               const float* __restrict__ W1,
                                               const float* __restrict__ W2,
                                               float* __restrict__ e1,
                                               float* __restrict__ e2) {
    __shared__ float sW[800];
    __shared__ float sWs[800];
    const float* W = (blockIdx.x == 0) ? W1 : W2;
    float* e = (blockIdx.x == 0) ? e1 : e2;
    int tid = threadIdx.x;
    for (int i = tid; i < 800; i += 256) sW[i] = W[i];
    __syncthreads();
    if (tid < 20) {
        float mx = -1e30f;
        for (int i = 0; i < 40; ++i) mx = fmaxf(mx, sW[i * 20 + tid]);
        float s = 0.f;
        for (int i = 0; i < 40; ++i) s += __expf(sW[i * 20 + tid] - mx);
        float inv = 1.f / s;
        for (int i = 0; i < 40; ++i) sWs[i * 20 + tid] = __expf(sW[i * 20 + tid] - mx) * inv;
    }
    __syncthreads();
    for (int row = tid; row < 512; row += 256) {
        float acc[20];
        #pragma unroll
        for (int j = 0; j < 20; ++j) acc[j] = 0.f;
        for (int i = 0; i < 40; ++i) {
            float ev = emb[row * 40 + i];
            #pragma unroll
            for (int j = 0; j < 20; ++j) acc[j] += ev * sWs[i * 20 + j];
        }
        float s = 0.f;
        #pragma unroll
        for (int j = 0; j < 20; ++j) s += acc[j] * acc[j];
        float scale = 1.f / (sqrtf(s) + 1e-8f);
        #pragma unroll
        for (int j = 0; j < 20; ++j) e[row * 20 + j] = acc[j] * scale;
    }
}

// ---------------------------------------------------------------------------
// K1: A[v][w] = adj>0 ? e1[v].e2[w] + adj : 9e-15 ; d[v] = 1/sqrt(rowsum)
// ---------------------------------------------------------------------------
__global__ __launch_bounds__(256) void k_adj(const float* __restrict__ adj,
                                             const float* __restrict__ e1,
                                             const float* __restrict__ e2,
                                             float* __restrict__ A,
                                             float* __restrict__ d) {
    int v = blockIdx.x, tid = threadIdx.x;
    __shared__ float ev[20];
    if (tid < 20) ev[tid] = e1[v * 20 + tid];
    __syncthreads();
    float local = 0.f;
    for (int w = tid; w < 512; w += 256) {
        float dot = 0.f;
        #pragma unroll
        for (int j = 0; j < 20; ++j) dot += ev[j] * e2[w * 20 + j];
        float av = adj[v * 512 + w];
        float Av = (av > 0.f) ? (dot + av) : 9e-15f;
        A[v * 512 + w] = Av;
        local += Av;
    }
    __shared__ float red[256];
    red[tid] = local;
    __syncthreads();
    for (int s = 128; s > 0; s >>= 1) {
        if (tid < s) red[tid] += red[tid + s];
        __syncthreads();
    }
    if (tid == 0) d[v] = 1.f / sqrtf(red[0]);
}

// ---------------------------------------------------------------------------
// K2: P slot1 = M[w][v] = Ls^T = -d[v]*d[w]*A[v][w] (bf16)
// ---------------------------------------------------------------------------
__global__ __launch_bounds__(256) void k_m(const float* __restrict__ A,
                                           const float* __restrict__ d,
                                           ushortT* __restrict__ P) {
    int w = blockIdx.x, tid = threadIdx.x;
    float dw = d[w];
    for (int v = tid; v < 512; v += 256) {
        float val = -d[v] * dw * A[v * 512 + w];
        P[512 * 512 + w * 512 + v] = f2bf(val);
    }
}

// ---------------------------------------------------------------------------
// K3: merged prep. Blocks 0..159: Wq build. Blocks 160+: x -> xbf convert.
// ---------------------------------------------------------------------------
__global__ __launch_bounds__(256) void k_prep(const float* __restrict__ x,
                                              ushortT* __restrict__ xbf,
                                              const float* __restrict__ mlp_w,
                                              ushortT* __restrict__ Wq) {
    int bx = blockIdx.x;
    if (bx < 160) {
        int idx = bx * 256 + threadIdx.x;
        if (idx >= 10 * 64 * 64) return;
        int q = idx >> 12, rem = idx & 4095, o = rem >> 6, c = rem & 63;
        float v;
        if (q == 0) {
            v = 0.f;
            #pragma unroll
            for (int k = 0; k < 4; ++k) v += mlp_w[o * 832 + k * 64 + c];
        } else {
            v = mlp_w[o * 832 + (q + 3) * 64 + c];
        }
        Wq[idx] = f2bf(v);
    } else {
        size_t i = (size_t)(bx - 160) * 256 + threadIdx.x;
        int c = (int)(i & 15) * 4;
        int v = (int)((i >> 4) & 511);
        int bt = (int)(i >> 13);            // b*12 + t
        int b = bt / 12, t = bt - b * 12;
        f32x4 f = *(const f32x4*)(x + (((size_t)b * 512 + v) * 12 + t) * 64 + c);
        us4 o = { f2bf(f[0]), f2bf(f[1]), f2bf(f[2]), f2bf(f[3]) };
        *(us4*)(xbf + ((size_t)bt * 512 + v) * 64 + c) = o;
    }
}

// ---------------------------------------------------------------------------
// 512x512x512 bf16 MFMA GEMM (+Chebyshev epilogue). Supports a second
// independent GEMM in blocks 64..127 (A2/B2/out3, mode 0).
// ---------------------------------------------------------------------------
__global__ __launch_bounds__(256) void k_gemm512(const ushortT* __restrict__ A,
                                                 const ushortT* __restrict__ B,
                                                 ushortT* __restrict__ out1,
                                                 ushortT* __restrict__ out2,
                                                 int mode,
                                                 const ushortT* __restrict__ aux,
                                                 const ushortT* __restrict__ A2,
                                                 const ushortT* __restrict__ B2,
                                                 ushortT* __restrict__ out3) {
    int bx = blockIdx.x;
    if (bx >= 64) { A = A2; B = B2; out1 = out3; out2 = nullptr; mode = 0; bx -= 64; }
    int wave = threadIdx.x >> 6, lane = threadIdx.x & 63;
    int lr = lane & 15, lg = lane >> 4;
    int mbase = (bx >> 3) * 64;
    int nbase = (bx & 7) * 64 + wave * 16;
    f32x4 acc[4] = {};
    for (int kk = 0; kk < 16; ++kk) {
        int k0 = kk * 32 + lg * 8;
        bf16x8 bfr;
        #pragma unroll
        for (int j = 0; j < 8; ++j) bfr[j] = (short)B[(k0 + j) * 512 + nbase + lr];
        #pragma unroll
        for (int wt = 0; wt < 4; ++wt) {
            bf16x8 af = *(const bf16x8*)(A + (mbase + wt * 16 + lr) * 512 + k0);
            acc[wt] = __builtin_amdgcn_mfma_f32_16x16x32_bf16(af, bfr, acc[wt], 0, 0, 0);
        }
    }
    #pragma unroll
    for (int wt = 0; wt < 4; ++wt)
        #pragma unroll
        for (int r = 0; r < 4; ++r) {
            int row = mbase + wt * 16 + lg * 4 + r;
            int col = nbase + lr;
            float v = acc[wt][r];
            out1[row * 512 + col] = f2bf(v);
            if (mode == 1) out2[row * 512 + col] = f2bf(2.f * v - (row == col ? 1.f : 0.f));
            else if (mode == 2) out2[row * 512 + col] = f2bf(4.f * v - 3.f * bf2f(aux[row * 512 + col]));
        }
}

// ---------------------------------------------------------------------------
// Main fused kernel v5:  out = relu(x + bias + sum_q P_q @ (X @ Wq^T))
//   Same structure as v4 (depth-4 ring, split zphase, padded Zt) but
//   __launch_bounds__(512, 2): hipcc's (512,4) derived a 64-VGPR cap ->
//   massive scratch spill (WRITE_SIZE 333MB). (512,2) -> cap >=128, no spill;
//   LDS (66.5KB) still allows 2 blocks/CU at HW level.
// ---------------------------------------------------------------------------
template<bool XBF>
__global__ __launch_bounds__(512, 2) void k_main(const float* __restrict__ x,
                                                 const ushortT* __restrict__ xbf,
                                                 const ushortT* __restrict__ P,
                                                 const ushortT* __restrict__ Wq,
                                                 const float* __restrict__ bias,
                                                 float* __restrict__ out) {
    __shared__ ushortT Zt[64 * ZLD];   // Z^T[o][v], padded stride
    const int SZ = 512 * 512;
    int bid = blockIdx.x;
    int b = bid / 24, rr = bid % 24, tt = rr >> 1, half = rr & 1;
    int tid = threadIdx.x, wave = tid >> 6, lane = tid & 63;
    int lr = lane & 15, lg = lane >> 4;
    int wbase = half * 256 + wave * 32;   // wave's 32 output rows
    int vbase = wave * 64;                // wave's 64 Z-compute rows

    const ushortT* xq = xbf + ((size_t)(b * 12 + tt) * 512 + vbase) * 64;
    const float*   xqf = x + ((size_t)(b * 512 + vbase) * 12 + tt) * 64;

    f32x4 oacc[2][4] = {};
    bf16x8 a0r[4], a1r[4];
    // preload ring (q=1, kk=0..3) — no barrier dependency, issue immediately
    {
        const ushortT* pq1 = P + (size_t)SZ + (size_t)(wbase + lr) * 512 + lg * 8;
        #pragma unroll
        for (int s = 0; s < 4; ++s) {
            a0r[s] = *(const bf16x8*)(pq1 + s * 32);
            a1r[s] = *(const bf16x8*)(pq1 + 8192 + s * 32);
        }
    }

    for (int q = 0; q <= 9; ++q) {
        // ---- zphase: Zt = (X @ Wq^T)^T, two vt-halves to cap reg peak ----
        const ushortT* wqp = Wq + q * 4096;
        #pragma unroll
        for (int h = 0; h < 2; ++h) {
            bf16x8 xf[4];
            #pragma unroll
            for (int j = 0; j < 2; ++j) {
                int vrow = (h * 2 + j) * 16 + lr;
                if (XBF) {
                    xf[j * 2 + 0] = *(const bf16x8*)(xq + vrow * 64 + lg * 8);
                    xf[j * 2 + 1] = *(const bf16x8*)(xq + vrow * 64 + 32 + lg * 8);
                } else {
                    const float* px = xqf + (size_t)vrow * 768 + lg * 8;
                    f32x4 f0 = *(const f32x4*)px;
                    f32x4 f1 = *(const f32x4*)(px + 4);
                    f32x4 f2 = *(const f32x4*)(px + 32);
                    f32x4 f3 = *(const f32x4*)(px + 36);
                    bf16x8 v0, v1;
                    v0[0] = (short)f2bf(f0[0]); v0[1] = (short)f2bf(f0[1]);
                    v0[2] = (short)f2bf(f0[2]); v0[3] = (short)f2bf(f0[3]);
                    v0[4] = (short)f2bf(f1[0]); v0[5] = (short)f2bf(f1[1]);
                    v0[6] = (short)f2bf(f1[2]); v0[7] = (short)f2bf(f1[3]);
                    v1[0] = (short)f2bf(f2[0]); v1[1] = (short)f2bf(f2[1]);
                    v1[2] = (short)f2bf(f2[2]); v1[3] = (short)f2bf(f2[3]);
                    v1[4] = (short)f2bf(f3[0]); v1[5] = (short)f2bf(f3[1]);
                    v1[6] = (short)f2bf(f3[2]); v1[7] = (short)f2bf(f3[3]);
                    xf[j * 2 + 0] = v0;
                    xf[j * 2 + 1] = v1;
                }
            }
            #pragma unroll
            for (int ot = 0; ot < 4; ++ot) {
                int o = ot * 16 + lr;
                bf16x8 wf0 = *(const bf16x8*)(wqp + o * 64 + lg * 8);
                bf16x8 wf1 = *(const bf16x8*)(wqp + o * 64 + 32 + lg * 8);
                f32x4 z0 = {}, z1 = {};
                z0 = __builtin_amdgcn_mfma_f32_16x16x32_bf16(xf[0], wf0, z0, 0, 0, 0);
                z0 = __builtin_amdgcn_mfma_f32_16x16x32_bf16(xf[1], wf1, z0, 0, 0, 0);
                z1 = __builtin_amdgcn_mfma_f32_16x16x32_bf16(xf[2], wf0, z1, 0, 0, 0);
                z1 = __builtin_amdgcn_mfma_f32_16x16x32_bf16(xf[3], wf1, z1, 0, 0, 0);
                int zb = o * ZLD;
                {
                    int v0i = vbase + (h * 2 + 0) * 16 + lg * 4;
                    us4 pk = { f2bf(z0[0]), f2bf(z0[1]), f2bf(z0[2]), f2bf(z0[3]) };
                    *(us4*)&Zt[zb + v0i] = pk;
                }
                {
                    int v0i = vbase + (h * 2 + 1) * 16 + lg * 4;
                    us4 pk = { f2bf(z1[0]), f2bf(z1[1]), f2bf(z1[2]), f2bf(z1[3]) };
                    *(us4*)&Zt[zb + v0i] = pk;
                }
            }
        }
        __syncthreads();

        if (q == 0) {
            // identity support: oacc = Z_0 directly
            #pragma unroll
            for (int wt = 0; wt < 2; ++wt)
                #pragma unroll
                for (int ot = 0; ot < 4; ++ot) {
                    int o = ot * 16 + lr;
                    int w0 = wbase + wt * 16 + lg * 4;
                    us4 z4 = *(const us4*)&Zt[o * ZLD + w0];
                    oacc[wt][ot][0] = bf2f(z4[0]);
                    oacc[wt][ot][1] = bf2f(z4[1]);
                    oacc[wt][ot][2] = bf2f(z4[2]);
                    oacc[wt][ot][3] = bf2f(z4[3]);
                }
        } else {
            const ushortT* pq  = P + (size_t)q * SZ + (size_t)(wbase + lr) * 512 + lg * 8;
            const ushortT* pqn = pq + SZ;
            #pragma unroll
            for (int kk = 0; kk < 16; ++kk) {
                const int slot = kk & 3;
                int vb = kk * 32 + lg * 8;
                bf16x8 b0 = *(const bf16x8*)&Zt[(0 * 16 + lr) * ZLD + vb];
                bf16x8 b1 = *(const bf16x8*)&Zt[(1 * 16 + lr) * ZLD + vb];
                bf16x8 b2 = *(const bf16x8*)&Zt[(2 * 16 + lr) * ZLD + vb];
                bf16x8 b3 = *(const bf16x8*)&Zt[(3 * 16 + lr) * ZLD + vb];
                oacc[0][0] = __builtin_amdgcn_mfma_f32_16x16x32_bf16(a0r[slot], b0, oacc[0][0], 0, 0, 0);
                oacc[1][0] = __builtin_amdgcn_mfma_f32_16x16x32_bf16(a1r[slot], b0, oacc[1][0], 0, 0, 0);
                oacc[0][1] = __builtin_amdgcn_mfma_f32_16x16x32_bf16(a0r[slot], b1, oacc[0][1], 0, 0, 0);
                oacc[1][1] = __builtin_amdgcn_mfma_f32_16x16x32_bf16(a1r[slot], b1, oacc[1][1], 0, 0, 0);
                oacc[0][2] = __builtin_amdgcn_mfma_f32_16x16x32_bf16(a0r[slot], b2, oacc[0][2], 0, 0, 0);
                oacc[1][2] = __builtin_amdgcn_mfma_f32_16x16x32_bf16(a1r[slot], b2, oacc[1][2], 0, 0, 0);
                oacc[0][3] = __builtin_amdgcn_mfma_f32_16x16x32_bf16(a0r[slot], b3, oacc[0][3], 0, 0, 0);
                oacc[1][3] = __builtin_amdgcn_mfma_f32_16x16x32_bf16(a1r[slot], b3, oacc[1][3], 0, 0, 0);
                if (kk < 12) {
                    a0r[slot] = *(const bf16x8*)(pq + (kk + 4) * 32);
                    a1r[slot] = *(const bf16x8*)(pq + 8192 + (kk + 4) * 32);
                } else if (q < 9) {
                    a0r[slot] = *(const bf16x8*)(pqn + (kk - 12) * 32);
                    a1r[slot] = *(const bf16x8*)(pqn + 8192 + (kk - 12) * 32);
                }
            }
        }
        __syncthreads();
    }

    // ---- epilogue: residual + bias + relu, fp32 out ----
    #pragma unroll
    for (int wt = 0; wt < 2; ++wt)
        #pragma unroll
        for (int ot = 0; ot < 4; ++ot)
            #pragma unroll
            for (int r = 0; r < 4; ++r) {
                int w = wbase + wt * 16 + lg * 4 + r;
                int o = ot * 16 + lr;
                size_t oi = (((size_t)b * 512 + w) * 12 + tt) * 64 + o;
                float v = oacc[wt][ot][r] + x[oi] + bias[o];
                out[oi] = (v > 0.f) ? v : 0.f;
            }
}

// ---------------------------------------------------------------------------
extern "C" void kernel_launch(void* const* d_in, const int* in_sizes, int n_in,
                              void* d_out, int out_size, void* d_ws, size_t ws_size,
                              hipStream_t stream) {
    const float* x    = (const float*)d_in[0];
    const float* adj  = (const float*)d_in[1];
    const float* emb  = (const float*)d_in[2];
    const float* W1   = (const float*)d_in[3];
    const float* W2   = (const float*)d_in[4];
    const float* mlpw = (const float*)d_in[5];
    const float* mlpb = (const float*)d_in[6];
    float* out = (float*)d_out;

    char* ws = (char*)d_ws;
    float*   e1   = (float*)(ws + 0);
    float*   e2   = (float*)(ws + 65536);
    float*   A    = (float*)(ws + 131072);
    float*   dvec = (float*)(ws + 1179648);
    ushortT* P    = (ushortT*)(ws + 1183744);            // [10][512][512] bf16 (slot0 unused)
    ushortT* Wq   = (ushortT*)(ws + 6426624);            // [10][64][64]  bf16
    ushortT* xbf  = (ushortT*)(ws + 6508544);            // [b][t][512][64] bf16 = 24MB
    const size_t WS_NEED = 6508544 + (size_t)32 * 12 * 512 * 64 * 2;
    const bool use_xbf = (ws_size >= WS_NEED);

    k_embed<<<2, 256, 0, stream>>>(emb, W1, W2, e1, e2);
    k_adj<<<512, 256, 0, stream>>>(adj, e1, e2, A, dvec);
    k_m<<<512, 256, 0, stream>>>(A, dvec, P);
    k_prep<<<use_xbf ? 12448 : 160, 256, 0, stream>>>(x, xbf, mlpw, Wq);

    const int SZ = 512 * 512;
    ushortT *S1 = P + 1 * SZ, *S2 = P + 2 * SZ, *S3 = P + 3 * SZ, *S4 = P + 4 * SZ,
            *S5 = P + 5 * SZ, *S6 = P + 6 * SZ, *S7 = P + 7 * SZ, *S8 = P + 8 * SZ,
            *S9 = P + 9 * SZ;
    // S2 = M^2 ; S4 = 2M^2 - I (T2^T)
    k_gemm512<<<64, 256, 0, stream>>>(S1, S1, S2, S4, 1, nullptr, nullptr, nullptr, nullptr);
    // S3 = M^3 ; S7 = 4M^3 - 3M (T3^T)  ||  S5 = (T2^T)^2
    k_gemm512<<<128, 256, 0, stream>>>(S1, S2, S3, S7, 2, S1, S4, S4, S5);
    // S6 = (T2^T)^3  ||  S8 = (T3^T)^2
    k_gemm512<<<128, 256, 0, stream>>>(S4, S5, S6, nullptr, 0, nullptr, S7, S7, S8);
    // S9 = (T3^T)^3
    k_gemm512<<<64, 256, 0, stream>>>(S7, S8, S9, nullptr, 0, nullptr, nullptr, nullptr, nullptr);

    if (use_xbf)
        k_main<true><<<768, 512, 0, stream>>>(x, xbf, P, Wq, mlpb, out);
    else
        k_main<false><<<768, 512, 0, stream>>>(x, nullptr, P, Wq, mlpb, out);
    (void)in_sizes; (void)n_in; (void)out_size;
}